// Round 2
// baseline (689.300 us; speedup 1.0000x reference)
//
#include <hip/hip_runtime.h>
#include <math.h>

typedef __bf16 bf16_t;
typedef __bf16 bf16x4 __attribute__((ext_vector_type(4)));
typedef __bf16 bf16x8 __attribute__((ext_vector_type(8)));
typedef float  f32x4  __attribute__((ext_vector_type(4)));

#define GLD16(gp, lp) __builtin_amdgcn_global_load_lds( \
    (const __attribute__((address_space(1))) void*)(gp), \
    (__attribute__((address_space(3))) void*)(lp), 16, 0, 0)

// ---------------- fp32 -> bf16 weight conversion ----------------
__global__ __launch_bounds__(256) void cvt_f32_bf16(
    const float* __restrict__ in, bf16_t* __restrict__ out, int n) {
  int i = (blockIdx.x * blockDim.x + threadIdx.x) * 4;
  if (i < n) {
    f32x4 v = *(const f32x4*)&in[i];
    bf16x4 o;
    o.x = (bf16_t)v.x; o.y = (bf16_t)v.y; o.z = (bf16_t)v.z; o.w = (bf16_t)v.w;
    *(bf16x4*)&out[i] = o;
  }
}

// ---------------- fused 3-branch LayerNorm -> bf16 concat ----------------
// grid: (rows, 3). block: 256 threads, H = 2048 -> 8 elems/thread.
__global__ __launch_bounds__(256) void ln3(
    const float* __restrict__ prevp, const float* __restrict__ utp,
    const float* __restrict__ ztp,
    const float* __restrict__ pg, const float* __restrict__ pb,
    const float* __restrict__ ug, const float* __restrict__ ub,
    const float* __restrict__ zg, const float* __restrict__ zb,
    bf16_t* __restrict__ outp, int H) {
  const int row = blockIdx.x;
  const int br  = blockIdx.y;
  const float* src = (br == 0) ? prevp : (br == 1) ? utp : ztp;
  const float* g   = (br == 0) ? pg : (br == 1) ? ug : zg;
  const float* b   = (br == 0) ? pb : (br == 1) ? ub : zb;
  src += (size_t)row * H;

  const int tid = threadIdx.x;
  const int h0  = tid * 8;

  f32x4 x0 = *(const f32x4*)&src[h0];
  f32x4 x1 = *(const f32x4*)&src[h0 + 4];

  float s = 0.f, s2 = 0.f;
#pragma unroll
  for (int r = 0; r < 4; ++r) {
    s  += x0[r] + x1[r];
    s2 += x0[r] * x0[r] + x1[r] * x1[r];
  }
#pragma unroll
  for (int o = 32; o; o >>= 1) {
    s  += __shfl_down(s, o);
    s2 += __shfl_down(s2, o);
  }
  __shared__ float red[8];
  const int wv = tid >> 6, ln = tid & 63;
  if (ln == 0) { red[wv] = s; red[4 + wv] = s2; }
  __syncthreads();
  s  = red[0] + red[1] + red[2] + red[3];
  s2 = red[4] + red[5] + red[6] + red[7];

  const float inv  = 1.0f / (float)H;
  const float mu   = s * inv;
  const float var  = s2 * inv - mu * mu;
  const float rstd = rsqrtf(var + 1e-5f);

  f32x4 g0 = *(const f32x4*)&g[h0];
  f32x4 g1 = *(const f32x4*)&g[h0 + 4];
  f32x4 b0 = *(const f32x4*)&b[h0];
  f32x4 b1v = *(const f32x4*)&b[h0 + 4];

  bf16x8 y;
#pragma unroll
  for (int r = 0; r < 4; ++r) {
    y[r]     = (bf16_t)((x0[r] - mu) * rstd * g0[r] + b0[r]);
    y[r + 4] = (bf16_t)((x1[r] - mu) * rstd * g1[r] + b1v[r]);
  }
  *(bf16x8*)&outp[(size_t)row * (3 * H) + (size_t)br * H + h0] = y;
}

// ---------------- NT bf16 GEMM (m97 structure): C[m,n]=sum_k A[m,k]*Bt[n,k] ----------------
// 128x128 tile, BK=32, 4 waves (2x2), each wave 64x64 via 4x4 of 16x16x32 MFMA.
template <int DO_GELU>
__global__ __launch_bounds__(256) void gemm_bt(
    const bf16_t* __restrict__ A, const bf16_t* __restrict__ Bt,
    const float* __restrict__ bias,
    float* __restrict__ Cf, bf16_t* __restrict__ Cb,
    int M, int N, int K) {
  constexpr int BM = 128, BN = 128, BK = 32;
  __shared__ __align__(16) bf16_t As[BM * BK];
  __shared__ __align__(16) bf16_t Bs[BN * BK];

  const int tid  = threadIdx.x;
  const int lane = tid & 63;
  const int wave = tid >> 6;
  const int ntn  = N / BN;
  const int bm   = blockIdx.x / ntn;
  const int bn   = blockIdx.x % ntn;
  const int wm   = (wave >> 1) * 64;  // wave row offset in tile
  const int wn   = (wave & 1) * 64;   // wave col offset in tile

  // staging: thread t stages 16B at row t/4, elem (t%4)*8; rows {t/4, t/4+64}
  const int srow = tid >> 2;
  const int scol = (tid & 3) * 8;
  const bf16_t* Ag = A  + (size_t)(bm * BM + srow) * K + scol;
  const bf16_t* Bg = Bt + (size_t)(bn * BN + srow) * K + scol;
  bf16_t* Al = &As[srow * BK + scol];  // byte off = tid*16 (lane-contiguous)
  bf16_t* Bl = &Bs[srow * BK + scol];

  // fragment read addr: row = wm/wn + i*16 + (lane&15), k = (lane>>4)*8 .. +7
  const int fr  = lane & 15;
  const int fko = (lane >> 4) * 8;
  const bf16_t* aRd = &As[(wm + fr) * BK + fko];
  const bf16_t* bRd = &Bs[(wn + fr) * BK + fko];

  f32x4 acc[4][4] = {};

  for (int k0 = 0; k0 < K; k0 += BK) {
    GLD16(Ag, Al);
    GLD16(Ag + (size_t)64 * K, Al + 64 * BK);
    GLD16(Bg, Bl);
    GLD16(Bg + (size_t)64 * K, Bl + 64 * BK);
    Ag += BK; Bg += BK;
    __syncthreads();  // drains vmcnt -> staged tile visible

    bf16x8 af[4], bf[4];
#pragma unroll
    for (int i = 0; i < 4; ++i) af[i] = *(const bf16x8*)(aRd + i * 16 * BK);
#pragma unroll
    for (int j = 0; j < 4; ++j) bf[j] = *(const bf16x8*)(bRd + j * 16 * BK);
#pragma unroll
    for (int i = 0; i < 4; ++i)
#pragma unroll
      for (int j = 0; j < 4; ++j)
        acc[i][j] = __builtin_amdgcn_mfma_f32_16x16x32_bf16(af[i], bf[j], acc[i][j], 0, 0, 0);
    __syncthreads();  // reads done before next stage overwrites
  }

  // epilogue: C/D layout col=lane&15, row=(lane>>4)*4+reg  [m89-verified]
  const int rbase = wm + ((lane >> 4) << 2);
  const int cbase = wn + (lane & 15);
#pragma unroll
  for (int i = 0; i < 4; ++i) {
#pragma unroll
    for (int j = 0; j < 4; ++j) {
      const int col = bn * BN + cbase + j * 16;
      const float bv = bias[col];
#pragma unroll
      for (int r = 0; r < 4; ++r) {
        const int row = bm * BM + rbase + i * 16 + r;
        float v = acc[i][j][r] + bv;
        if constexpr (DO_GELU) {
          v = 0.5f * v * (1.0f + erff(v * 0.70710678118654752f));
          Cb[(size_t)row * N + col] = (bf16_t)v;
        } else {
          Cf[(size_t)row * N + col] = v;
        }
      }
    }
  }
}

extern "C" void kernel_launch(void* const* d_in, const int* in_sizes, int n_in,
                              void* d_out, int out_size, void* d_ws, size_t ws_size,
                              hipStream_t stream) {
  const float* u_t    = (const float*)d_in[0];
  const float* z_t    = (const float*)d_in[1];
  const float* prev   = (const float*)d_in[2];
  const float* prev_g = (const float*)d_in[3];
  const float* prev_b = (const float*)d_in[4];
  const float* u_g    = (const float*)d_in[5];
  const float* u_b    = (const float*)d_in[6];
  const float* z_g    = (const float*)d_in[7];
  const float* z_b    = (const float*)d_in[8];
  const float* W1     = (const float*)d_in[9];
  const float* b1     = (const float*)d_in[10];
  const float* W2     = (const float*)d_in[11];
  const float* b2     = (const float*)d_in[12];

  const int H    = in_sizes[3];        // 2048
  const int CH   = in_sizes[10];       // 512
  const int rows = in_sizes[0] / H;    // 16384
  const int IN   = 3 * H;              // 6144

  bf16_t* inpB = (bf16_t*)d_ws;                      // [rows, IN]
  bf16_t* w1B  = inpB + (size_t)rows * IN;           // [CH, IN]
  bf16_t* w2B  = w1B + (size_t)CH * IN;              // [H, CH]
  bf16_t* hidB = w2B + (size_t)H * CH;               // [rows, CH]

  // weights -> bf16
  {
    int n1 = CH * IN;
    cvt_f32_bf16<<<dim3((n1 / 4 + 255) / 256), dim3(256), 0, stream>>>(W1, w1B, n1);
    int n2 = H * CH;
    cvt_f32_bf16<<<dim3((n2 / 4 + 255) / 256), dim3(256), 0, stream>>>(W2, w2B, n2);
  }
  // 3x LayerNorm -> concat bf16 (order: prev, u, z)
  ln3<<<dim3(rows, 3), dim3(256), 0, stream>>>(prev, u_t, z_t, prev_g, prev_b,
                                               u_g, u_b, z_g, z_b, inpB, H);
  // GEMM1 + bias + exact GELU -> bf16 hidden [rows, CH]
  gemm_bt<1><<<dim3((rows / 128) * (CH / 128)), dim3(256), 0, stream>>>(
      inpB, w1B, b1, nullptr, hidB, rows, CH, IN);
  // GEMM2 + bias -> fp32 out [rows, H]
  gemm_bt<0><<<dim3((rows / 128) * (H / 128)), dim3(256), 0, stream>>>(
      hidB, w2B, b2, (float*)d_out, nullptr, rows, H, CH);
}